// Round 4
// baseline (687.328 us; speedup 1.0000x reference)
//
#include <hip/hip_runtime.h>
#include <stdint.h>

typedef unsigned short u16;
typedef __attribute__((ext_vector_type(8))) short short8;
typedef __attribute__((ext_vector_type(4))) float f32x4;

constexpr int SEQ   = 2048;
constexpr int HID   = 1024;
constexpr int NHEAD = 16;
constexpr int QKVD  = 1536;   // (16 + 2*4) * 64
constexpr int FFI   = 2816;
constexpr int NEXP  = 8;
constexpr int WINSZ = 512;
#define EPSF 1e-5f

__device__ __forceinline__ u16 f2bf(float f) {
  union { unsigned int i; float f; } v; v.f = f;
  unsigned int i = v.i;
  return (u16)((i + 0x7fffu + ((i >> 16) & 1u)) >> 16);
}

__device__ __forceinline__ ushort4 f2bf4(float4 v) {
  ushort4 o;
  o.x = f2bf(v.x); o.y = f2bf(v.y); o.z = f2bf(v.z); o.w = f2bf(v.w);
  return o;
}

__device__ __forceinline__ void gload_lds16(const void* g, void* l) {
  __builtin_amdgcn_global_load_lds((__attribute__((address_space(1))) void*)g,
                                   (__attribute__((address_space(3))) void*)l,
                                   16, 0, 0);
}

#define MFMA_BF16(a, b, c) __builtin_amdgcn_mfma_f32_16x16x32_bf16(a, b, c, 0, 0, 0)

constexpr int NATTN_BLK = (SEQ / 64) * NHEAD;  // 512

// ---------------- RMSNorm (f32 in -> bf16 out) ----------------
__global__ __launch_bounds__(256) void k_prep(const float* __restrict__ x,
                                              const float* __restrict__ w,
                                              u16* __restrict__ y) {
  const int bid = blockIdx.x, tid = threadIdx.x;
  const int wid = tid >> 6, lane = tid & 63;
  __shared__ float red[4];
  const float* xr = x + (size_t)bid * HID;
  float4 v = *(const float4*)&xr[tid * 4];
  float ss = v.x * v.x + v.y * v.y + v.z * v.z + v.w * v.w;
#pragma unroll
  for (int m = 1; m < 64; m <<= 1) ss += __shfl_xor(ss, m);
  if (lane == 0) red[wid] = ss;
  __syncthreads();
  ss = red[0] + red[1] + red[2] + red[3];
  float sc = rsqrtf(ss * (1.0f / HID) + EPSF);
  float4 wv = *(const float4*)&w[tid * 4];
  ushort4 o;
  o.x = f2bf(v.x * sc * wv.x);
  o.y = f2bf(v.y * sc * wv.y);
  o.z = f2bf(v.z * sc * wv.z);
  o.w = f2bf(v.w * sc * wv.w);
  *(ushort4*)&y[(size_t)bid * HID + tid * 4] = o;
}

// ---- C = A(MxK,bf16) * B(NxK,f32)^T, 128x64 tile ----
// B is read f32 and converted to bf16 during reg-staged LDS write (pad 72).
// gridDim.z > 1: split-K, f32 plane per z. wf32==0: bf16 out (z must be 1).
__global__ __launch_bounds__(256, 2) void k_gemm_bt(
    const u16* __restrict__ A, const float* __restrict__ B,
    void* __restrict__ Cout, int N, int K, int KT, int wf32) {
  __shared__ u16 As[128 * 64];
  __shared__ u16 Bs[64 * 72];
  const int tid = threadIdx.x, wid = tid >> 6, lane = tid & 63;
  const int quad = lane >> 4, l16 = lane & 15;
  const int wr = wid >> 1, wc = wid & 1;
  const int m0 = blockIdx.y * 128, n0 = blockIdx.x * 64;
  const int M = gridDim.y * 128;
  const int kbase = blockIdx.z * KT * 64;
  const int sr = lane >> 3, sc = (lane & 7) * 8;
  // B staging map: 64 rows x 64 f32; 4 lanes/row, 16 f32 per lane
  const int brow = wid * 16 + (lane >> 2);
  const int bk = (lane & 3) * 16;
  f32x4 acc[4][2] = {};
  for (int kt = 0; kt < KT; ++kt) {
    const int k0 = kbase + (kt << 6);
    const float* bp = &B[(size_t)(n0 + brow) * K + k0 + bk];
    float4 bv0 = *(const float4*)&bp[0];
    float4 bv1 = *(const float4*)&bp[4];
    float4 bv2 = *(const float4*)&bp[8];
    float4 bv3 = *(const float4*)&bp[12];
#pragma unroll
    for (int it = 0; it < 4; ++it) {
      int seg = wid * 4 + it;
      int row = seg * 8 + sr;
      gload_lds16(&A[(size_t)(m0 + row) * K + k0 + sc], &As[seg * 512]);
    }
    *(ushort4*)&Bs[brow * 72 + bk + 0]  = f2bf4(bv0);
    *(ushort4*)&Bs[brow * 72 + bk + 4]  = f2bf4(bv1);
    *(ushort4*)&Bs[brow * 72 + bk + 8]  = f2bf4(bv2);
    *(ushort4*)&Bs[brow * 72 + bk + 12] = f2bf4(bv3);
    __syncthreads();
#pragma unroll
    for (int ks = 0; ks < 2; ++ks) {
      short8 af[4], bf[2];
#pragma unroll
      for (int t = 0; t < 4; ++t)
        af[t] = *(const short8*)&As[(64 * wr + 16 * t + l16) * 64 + ks * 32 + quad * 8];
#pragma unroll
      for (int t = 0; t < 2; ++t)
        bf[t] = *(const short8*)&Bs[(32 * wc + 16 * t + l16) * 72 + ks * 32 + quad * 8];
#pragma unroll
      for (int mt = 0; mt < 4; ++mt)
#pragma unroll
        for (int nt = 0; nt < 2; ++nt)
          acc[mt][nt] = MFMA_BF16(af[mt], bf[nt], acc[mt][nt]);
    }
    __syncthreads();
  }
  if (wf32) {
    float* C = (float*)Cout + (size_t)blockIdx.z * M * N;
#pragma unroll
    for (int mt = 0; mt < 4; ++mt)
#pragma unroll
      for (int r = 0; r < 4; ++r) {
        int row = m0 + 64 * wr + 16 * mt + quad * 4 + r;
#pragma unroll
        for (int nt = 0; nt < 2; ++nt) {
          int col = n0 + 32 * wc + 16 * nt + l16;
          C[(size_t)row * N + col] = acc[mt][nt][r];
        }
      }
  } else {
    u16* C = (u16*)Cout;
#pragma unroll
    for (int mt = 0; mt < 4; ++mt)
#pragma unroll
      for (int r = 0; r < 4; ++r) {
        int row = m0 + 64 * wr + 16 * mt + quad * 4 + r;
#pragma unroll
        for (int nt = 0; nt < 2; ++nt) {
          int col = n0 + 32 * wc + 16 * nt + l16;
          C[(size_t)row * N + col] = f2bf(acc[mt][nt][r]);
        }
      }
  }
}

// ------- sliding-window GQA flash attention (pure; no fused convert) ----
__global__ __launch_bounds__(256, 2) void k_attn(const u16* __restrict__ qkv,
                                                 u16* __restrict__ o) {
  const int bid = blockIdx.x;
  const int tid = threadIdx.x;
  const int qb = bid & 31;
  const int h  = bid >> 5;
  const int q0 = qb * 64;
  const int g = h >> 2;
  __shared__ u16 Qs[64 * 72], Ks[64 * 72], Vt[64 * 72], Ps[64 * 72];
  const int wid = tid >> 6, lane = tid & 63;
  const int quad = lane >> 4, l16 = lane & 15;

#pragma unroll
  for (int it = 0; it < 2; ++it) {
    int idx = it * 256 + tid;
    int row = idx >> 3, c8 = (idx & 7) * 8;
    *(short8*)&Qs[row * 72 + c8] =
        *(const short8*)&qkv[(size_t)(q0 + row) * QKVD + h * 64 + c8];
  }

  f32x4 oacc[4] = {};
  float mrun[4], lrun[4];
#pragma unroll
  for (int r = 0; r < 4; ++r) { mrun[r] = -1e30f; lrun[r] = 0.f; }

  const int ktlo = (q0 >= WINSZ) ? ((q0 - WINSZ + 1) >> 6) : 0;
  const int kthi = qb;
  for (int kt = ktlo; kt <= kthi; ++kt) {
#pragma unroll
    for (int it = 0; it < 2; ++it) {
      int idx = it * 256 + tid;
      int row = idx >> 3, c8 = (idx & 7) * 8;
      *(short8*)&Ks[row * 72 + c8] =
          *(const short8*)&qkv[(size_t)(kt * 64 + row) * QKVD + 1024 + g * 64 + c8];
    }
#pragma unroll
    for (int it = 0; it < 8; ++it) {
      int idx = it * 256 + tid;
      int key = idx >> 5;
      int d = (idx & 31) * 2;
      unsigned int u = *(const unsigned int*)&qkv[(size_t)(kt * 64 + key) * QKVD + 1280 + g * 64 + d];
      Vt[d * 72 + key] = (u16)(u & 0xffffu);
      Vt[(d + 1) * 72 + key] = (u16)(u >> 16);
    }
    __syncthreads();

    f32x4 sa[4] = {};
#pragma unroll
    for (int ks = 0; ks < 2; ++ks) {
      short8 af = *(const short8*)&Qs[(16 * wid + l16) * 72 + ks * 32 + quad * 8];
#pragma unroll
      for (int ct = 0; ct < 4; ++ct) {
        short8 bf = *(const short8*)&Ks[(16 * ct + l16) * 72 + ks * 32 + quad * 8];
        sa[ct] = MFMA_BF16(af, bf, sa[ct]);
      }
    }

    float pvv[4][4];
#pragma unroll
    for (int r = 0; r < 4; ++r) {
      int i = q0 + 16 * wid + quad * 4 + r;
      float mx = -1e30f;
#pragma unroll
      for (int ct = 0; ct < 4; ++ct) {
        int j = kt * 64 + 16 * ct + l16;
        float v = sa[ct][r] * 0.125f;
        bool ok = (j <= i) && (i - j < WINSZ);
        v = ok ? v : -1e30f;
        pvv[ct][r] = v;
        mx = fmaxf(mx, v);
      }
#pragma unroll
      for (int m = 1; m < 16; m <<= 1) mx = fmaxf(mx, __shfl_xor(mx, m));
      float mnew = fmaxf(mrun[r], mx);
      float alpha = __expf(mrun[r] - mnew);
      float s = 0.f;
#pragma unroll
      for (int ct = 0; ct < 4; ++ct) {
        float p = (pvv[ct][r] > -1e29f) ? __expf(pvv[ct][r] - mnew) : 0.f;
        pvv[ct][r] = p;
        s += p;
      }
#pragma unroll
      for (int m = 1; m < 16; m <<= 1) s += __shfl_xor(s, m);
      lrun[r] = lrun[r] * alpha + s;
      mrun[r] = mnew;
#pragma unroll
      for (int ct = 0; ct < 4; ++ct) oacc[ct][r] *= alpha;
    }
#pragma unroll
    for (int ct = 0; ct < 4; ++ct)
#pragma unroll
      for (int r = 0; r < 4; ++r)
        Ps[(16 * wid + quad * 4 + r) * 72 + 16 * ct + l16] = f2bf(pvv[ct][r]);
    __syncthreads();

#pragma unroll
    for (int ks = 0; ks < 2; ++ks) {
      short8 af = *(const short8*)&Ps[(16 * wid + l16) * 72 + ks * 32 + quad * 8];
#pragma unroll
      for (int ct = 0; ct < 4; ++ct) {
        short8 bf = *(const short8*)&Vt[(16 * ct + l16) * 72 + ks * 32 + quad * 8];
        oacc[ct] = MFMA_BF16(af, bf, oacc[ct]);
      }
    }
    __syncthreads();
  }

#pragma unroll
  for (int ct = 0; ct < 4; ++ct)
#pragma unroll
    for (int r = 0; r < 4; ++r) {
      int row = q0 + 16 * wid + quad * 4 + r;
      float v = oacc[ct][r] / lrun[r];
      o[(size_t)row * HID + h * 64 + 16 * ct + l16] = f2bf(v);
    }
}

// --------- RMSNorm2 + router top-2 (sums O-proj splits + residual) -------
__global__ __launch_bounds__(256) void k_rms2_router(
    const float* __restrict__ o0, const float* __restrict__ o1,
    const float* __restrict__ hs, const float* __restrict__ ln2,
    const float* __restrict__ rw, float* __restrict__ out1,
    u16* __restrict__ T, int* __restrict__ counts,
    int* __restrict__ tok_idx, int* __restrict__ tok_slot,
    float* __restrict__ tok_pw) {
  const int tkn = blockIdx.x, tid = threadIdx.x, wid = tid >> 6, lane = tid & 63;
  const size_t base = (size_t)tkn * HID + tid * 4;
  float4 a = *(const float4*)&o0[base];
  float4 b = *(const float4*)&o1[base];
  float4 h = *(const float4*)&hs[base];
  float4 v;
  v.x = a.x + b.x + h.x; v.y = a.y + b.y + h.y;
  v.z = a.z + b.z + h.z; v.w = a.w + b.w + h.w;
  *(float4*)&out1[base] = v;
  float ss = v.x * v.x + v.y * v.y + v.z * v.z + v.w * v.w;
#pragma unroll
  for (int m = 1; m < 64; m <<= 1) ss += __shfl_xor(ss, m);
  __shared__ float red[4];
  if (lane == 0) red[wid] = ss;
  __syncthreads();
  ss = red[0] + red[1] + red[2] + red[3];
  float sc = rsqrtf(ss * (1.0f / HID) + EPSF);
  float4 lw = *(const float4*)&ln2[tid * 4];
  float t0 = v.x * sc * lw.x;
  float t1 = v.y * sc * lw.y;
  float t2 = v.z * sc * lw.z;
  float t3 = v.w * sc * lw.w;
  ushort4 o;
  o.x = f2bf(t0); o.y = f2bf(t1); o.z = f2bf(t2); o.w = f2bf(t3);
  *(ushort4*)&T[(size_t)tkn * HID + tid * 4] = o;

  float p[8];
#pragma unroll
  for (int e = 0; e < 8; ++e) {
    float4 r = *(const float4*)&rw[e * HID + tid * 4];
    p[e] = t0 * r.x + t1 * r.y + t2 * r.z + t3 * r.w;
  }
#pragma unroll
  for (int e = 0; e < 8; ++e)
#pragma unroll
    for (int m = 1; m < 64; m <<= 1) p[e] += __shfl_xor(p[e], m);
  __shared__ float pr[4][8];
  if (lane == 0)
#pragma unroll
    for (int e = 0; e < 8; ++e) pr[wid][e] = p[e];
  __syncthreads();
  if (tid == 0) {
    float lg[8];
#pragma unroll
    for (int e = 0; e < 8; ++e) lg[e] = pr[0][e] + pr[1][e] + pr[2][e] + pr[3][e];
    float mx = lg[0];
#pragma unroll
    for (int e = 1; e < 8; ++e) mx = fmaxf(mx, lg[e]);
    float ex[8], se = 0.f;
#pragma unroll
    for (int e = 0; e < 8; ++e) { ex[e] = __expf(lg[e] - mx); se += ex[e]; }
    int b0 = 0;
#pragma unroll
    for (int e = 1; e < 8; ++e) if (lg[e] > lg[b0]) b0 = e;
    int b1 = (b0 == 0) ? 1 : 0;
#pragma unroll
    for (int e = 0; e < 8; ++e) if (e != b0 && lg[e] > lg[b1]) b1 = e;
    float inv = 1.0f / se;
    int s0 = atomicAdd(&counts[b0], 1);
    tok_idx[b0 * SEQ + s0] = tkn;
    tok_slot[2 * tkn] = b0 * SEQ + s0;
    tok_pw[2 * tkn] = ex[b0] * inv;
    int s1 = atomicAdd(&counts[b1], 1);
    tok_idx[b1 * SEQ + s1] = tkn;
    tok_slot[2 * tkn + 1] = b1 * SEQ + s1;
    tok_pw[2 * tkn + 1] = ex[b1] * inv;
  }
}

__global__ void k_offsets(const int* __restrict__ counts, int* __restrict__ offs) {
  if (threadIdx.x == 0 && blockIdx.x == 0) {
    int s = 0;
    for (int e = 0; e < NEXP; ++e) { offs[e] = s; s += counts[e]; }
    offs[NEXP] = s;
  }
}

// -- MoE up GEMM: 256m x (64g + 64u), 8 waves; B read f32 + reg-convert --
__global__ __launch_bounds__(512, 4) void k_moe_gu(
    const u16* __restrict__ T, const float* __restrict__ Wgu,
    const int* __restrict__ counts, const int* __restrict__ offs,
    const int* __restrict__ tok_idx, u16* __restrict__ Abuf) {
  const int e = blockIdx.z;
  const int cnt = counts[e];
  const int m0 = blockIdx.y * 256;
  if (m0 >= cnt) return;
  const int n0 = blockIdx.x * 64;
  const float* We = Wgu + (size_t)e * 2 * FFI * HID;
  const int* ti = tok_idx + e * SEQ;
  const int aoff = offs[e];
  __shared__ u16 As[256 * 64], Bg[64 * 72], Bu[64 * 72];
  const int tid = threadIdx.x, wid = tid >> 6, lane = tid & 63;
  const int quad = lane >> 4, l16 = lane & 15;
  const int wr = wid >> 1, wc = wid & 1;  // wr: m-quarter 0..3, wc: n-half
  const int sr = lane >> 3, sc = (lane & 7) * 8;
  // B staging map: 64 rows; 8 lanes/row, 8 f32 per lane
  const int brow = wid * 8 + (lane >> 3);
  const int bk = (lane & 7) * 8;
  int tokrow[4];
#pragma unroll
  for (int it = 0; it < 4; ++it) {
    int row = (wid * 4 + it) * 8 + sr;   // seg 0..31 -> rows 0..255
    int ra = m0 + row;
    if (ra > cnt - 1) ra = cnt - 1;
    tokrow[it] = ti[ra];
  }
  f32x4 accg[4][2] = {}, accu[4][2] = {};
  for (int kt = 0; kt < 16; ++kt) {
    const int k0 = kt << 6;
    const float* gp = &We[(size_t)(n0 + brow) * HID + k0 + bk];
    const float* up = &We[(size_t)(FFI + n0 + brow) * HID + k0 + bk];
    float4 g0 = *(const float4*)&gp[0];
    float4 g1 = *(const float4*)&gp[4];
    float4 u0 = *(const float4*)&up[0];
    float4 u1 = *(const float4*)&up[4];
#pragma unroll
    for (int it = 0; it < 4; ++it) {
      int seg = wid * 4 + it;
      gload_lds16(&T[(size_t)tokrow[it] * HID + k0 + sc], &As[seg * 512]);
    }
    *(ushort4*)&Bg[brow * 72 + bk + 0] = f2bf4(g0);
    *(ushort4*)&Bg[brow * 72 + bk + 4] = f2bf4(g1);
    *(ushort4*)&Bu[brow * 72 + bk + 0] = f2bf4(u0);
    *(ushort4*)&Bu[brow * 72 + bk + 4] = f2bf4(u1);
    __syncthreads();
#pragma unroll
    for (int ks = 0; ks < 2; ++ks) {
      short8 af[4], bg[2], bu[2];
#pragma unroll
      for (int t = 0; t < 4; ++t)
        af[t] = *(const short8*)&As[(64 * wr + 16 * t + l16) * 64 + ks * 32 + quad * 8];
#pragma unroll
      for (int t = 0; t < 2; ++t) {
        bg[t] = *(const short8*)&Bg[(32 * wc + 16 * t + l16) * 72 + ks * 32 + quad * 8];
        bu[t] = *(const short8*)&Bu[(32 * wc + 16 * t + l16) * 72 + ks * 32 + quad * 8];
      }
#pragma unroll
      for (int mt = 0; mt < 4; ++mt)
#pragma unroll
        for (int nt = 0; nt < 2; ++nt) {
          accg[mt][nt] = MFMA_BF16(af[mt], bg[nt], accg[mt][nt]);
          accu[mt][nt] = MFMA_BF16(af[mt], bu[nt], accu[mt][nt]);
        }
    }
    __syncthreads();
  }
#pragma unroll
  for (int mt = 0; mt < 4; ++mt)
#pragma unroll
    for (int r = 0; r < 4; ++r) {
      int rl = 64 * wr + 16 * mt + quad * 4 + r;
      int grow = m0 + rl;
      if (grow < cnt) {
        size_t rbase = (size_t)(aoff + grow) * FFI;
#pragma unroll
        for (int nt = 0; nt < 2; ++nt) {
          int col = n0 + 32 * wc + 16 * nt + l16;
          float gv = accg[mt][nt][r];
          float uv = accu[mt][nt][r];
          float a = gv / (1.0f + __expf(-gv)) * uv;
          Abuf[rbase + col] = f2bf(a);
        }
      }
    }
}

// -- MoE down GEMM, split-K x2; B read f32 + reg-convert; f32 slot stores --
__global__ __launch_bounds__(256, 2) void k_moe_y(
    const u16* __restrict__ Abuf, const float* __restrict__ W2,
    const int* __restrict__ counts, const int* __restrict__ offs,
    float* __restrict__ ybuf) {
  const int e = blockIdx.z >> 1;
  const int sk = blockIdx.z & 1;
  const int cnt = counts[e];
  const int m0 = blockIdx.y * 128;
  if (m0 >= cnt) return;
  const int n0 = blockIdx.x * 128;
  const int kbase = sk * 1408;  // 2816 / 2
  const float* We = W2 + (size_t)e * HID * FFI;
  const int aoff = offs[e];
  __shared__ u16 As[128 * 64], Bs[128 * 72];
  const int tid = threadIdx.x, wid = tid >> 6, lane = tid & 63;
  const int quad = lane >> 4, l16 = lane & 15;
  const int wr = wid >> 1, wc = wid & 1;
  const int sr = lane >> 3, sc = (lane & 7) * 8;
  // B staging map: 128 rows; 2 lanes/row, 32 f32 per lane
  const int brow = wid * 32 + (lane >> 1);
  const int bk = (lane & 1) * 32;
  int arow[4];
#pragma unroll
  for (int it = 0; it < 4; ++it) {
    int row = (wid * 4 + it) * 8 + sr;
    int ra = m0 + row;
    if (ra > cnt - 1) ra = cnt - 1;
    arow[it] = aoff + ra;
  }
  f32x4 acc[4][4] = {};
  for (int kt = 0; kt < 22; ++kt) {
    const int k0 = kbase + (kt << 6);
    const float* bp = &We[(size_t)(n0 + brow) * FFI + k0 + bk];
    float4 bv[8];
#pragma unroll
    for (int j = 0; j < 8; ++j) bv[j] = *(const float4*)&bp[4 * j];
#pragma unroll
    for (int it = 0; it < 4; ++it) {
      int seg = wid * 4 + it;
      gload_lds16(&Abuf[(size_t)arow[it] * FFI + k0 + sc], &As[seg * 512]);
    }
#pragma unroll
    for (int j = 0; j < 8; ++j)
      *(ushort4*)&Bs[brow * 72 + bk + 4 * j] = f2bf4(bv[j]);
    __syncthreads();
#pragma unroll
    for (int ks = 0; ks < 2; ++ks) {
      short8 af[4], bf[4];
#pragma unroll
      for (int t = 0; t < 4; ++t)
        af[t] = *(const short8*)&As[(64 * wr + 16 * t + l16) * 64 + ks * 32 + quad * 8];
#pragma unroll
      for (int t = 0; t < 4; ++t)
        bf[t] = *(const short8*)&Bs[(64 * wc + 16 * t + l16) * 72 + ks * 32 + quad * 8];
#pragma unroll
      for (int mt = 0; mt < 4; ++mt)
#pragma unroll
        for (int nt = 0; nt < 4; ++nt)
          acc[mt][nt] = MFMA_BF16(af[mt], bf[nt], acc[mt][nt]);
    }
    __syncthreads();
  }
  float* Y = ybuf + (size_t)sk * 2 * SEQ * HID;
#pragma unroll
  for (int mt = 0; mt < 4; ++mt)
#pragma unroll
    for (int r = 0; r < 4; ++r) {
      int rl = 64 * wr + 16 * mt + quad * 4 + r;
      int grow = m0 + rl;
      if (grow < cnt) {
        size_t obase = (size_t)(aoff + grow) * HID;
#pragma unroll
        for (int nt = 0; nt < 4; ++nt) {
          int col = n0 + 64 * wc + 16 * nt + l16;
          Y[obase + col] = acc[mt][nt][r];
        }
      }
    }
}

// ---- final gather: out[t] = w0*(y0[s0]+y1[s0]) + w1*(y0[s1]+y1[s1]) ----
__global__ __launch_bounds__(256) void k_moe_out(
    const float* __restrict__ yb, const int* __restrict__ offs,
    const int* __restrict__ tok_slot, const float* __restrict__ tok_pw,
    float* __restrict__ out0) {
  const int t = blockIdx.x, tid = threadIdx.x;
  const int v0 = tok_slot[2 * t], v1 = tok_slot[2 * t + 1];
  const float w0 = tok_pw[2 * t], w1 = tok_pw[2 * t + 1];
  const size_t g0 = (size_t)(offs[v0 >> 11] + (v0 & (SEQ - 1))) * HID;
  const size_t g1 = (size_t)(offs[v1 >> 11] + (v1 & (SEQ - 1))) * HID;
  const size_t YP = (size_t)2 * SEQ * HID;
  const int c = tid * 4;
  float4 a0 = *(const float4*)&yb[g0 + c];
  float4 b0 = *(const float4*)&yb[YP + g0 + c];
  float4 a1 = *(const float4*)&yb[g1 + c];
  float4 b1 = *(const float4*)&yb[YP + g1 + c];
  float4 r;
  r.x = w0 * (a0.x + b0.x) + w1 * (a1.x + b1.x);
  r.y = w0 * (a0.y + b0.y) + w1 * (a1.y + b1.y);
  r.z = w0 * (a0.z + b0.z) + w1 * (a1.z + b1.z);
  r.w = w0 * (a0.w + b0.w) + w1 * (a1.w + b1.w);
  *(float4*)&out0[(size_t)t * HID + c] = r;
}

extern "C" void kernel_launch(void* const* d_in, const int* in_sizes, int n_in,
                              void* d_out, int out_size, void* d_ws, size_t ws_size,
                              hipStream_t stream) {
  const float* hs   = (const float*)d_in[0];
  const float* wqkv = (const float*)d_in[2];
  const float* wo   = (const float*)d_in[3];
  const float* rwt  = (const float*)d_in[4];
  const float* wsx  = (const float*)d_in[5];
  const float* w2s  = (const float*)d_in[6];
  const float* ln1  = (const float*)d_in[7];
  const float* ln2  = (const float*)d_in[8];
  float* out0 = (float*)d_out;                       // MoE output (f32)
  float* out1 = out0 + (size_t)SEQ * HID;            // residual2 (f32)

  char* p = (char*)d_ws;
  u16* xn       = (u16*)p;   p += (size_t)SEQ * HID * 2;
  u16* qkv      = (u16*)p;   p += (size_t)SEQ * QKVD * 2;
  u16* ob       = (u16*)p;   p += (size_t)SEQ * HID * 2;
  float* of     = (float*)p; p += (size_t)2 * SEQ * HID * 4;  // 2 split planes
  int* counts   = (int*)p;   p += 32;
  int* offs     = (int*)p;   p += 64;
  int* tok_idx  = (int*)p;   p += (size_t)NEXP * SEQ * 4;
  int* tok_slot = (int*)p;   p += (size_t)2 * SEQ * 4;
  float* tok_pw = (float*)p; p += (size_t)2 * SEQ * 4;
  u16* abuf     = (u16*)p;   p += (size_t)2 * SEQ * FFI * 2;
  float* ybuf   = (float*)p; p += (size_t)2 * 2 * SEQ * HID * 4;  // 2 sk planes

  u16* tb = xn;  // alias: xn dead after QKV GEMM

  hipMemsetAsync(counts, 0, 32, stream);

  k_prep<<<SEQ, 256, 0, stream>>>(hs, ln1, xn);
  // QKV: M=2048, N=1536, K=1024, full-K, bf16 epilogue (B = f32 wqkv direct)
  k_gemm_bt<<<dim3(QKVD / 64, SEQ / 128, 1), 256, 0, stream>>>(
      xn, wqkv, qkv, QKVD, HID, 16, 0);
  k_attn<<<NATTN_BLK, 256, 0, stream>>>(qkv, ob);
  // O-proj: M=2048, N=1024, K=1024, split-K x2 (B = f32 wo direct)
  k_gemm_bt<<<dim3(HID / 64, SEQ / 128, 2), 256, 0, stream>>>(
      ob, wo, of, HID, HID, 8, 1);
  k_rms2_router<<<SEQ, 256, 0, stream>>>(of, of + (size_t)SEQ * HID, hs, ln2,
                                         rwt, out1, tb, counts, tok_idx,
                                         tok_slot, tok_pw);
  k_offsets<<<1, 64, 0, stream>>>(counts, offs);
  k_moe_gu<<<dim3(FFI / 64, SEQ / 256, NEXP), 512, 0, stream>>>(
      tb, wsx, counts, offs, tok_idx, abuf);
  k_moe_y<<<dim3(HID / 128, SEQ / 128, NEXP * 2), 256, 0, stream>>>(
      abuf, w2s, counts, offs, ybuf);
  k_moe_out<<<SEQ, 256, 0, stream>>>(ybuf, offs, tok_slot, tok_pw, out0);
}

// Round 5
// 677.988 us; speedup vs baseline: 1.0138x; 1.0138x over previous
//
#include <hip/hip_runtime.h>
#include <stdint.h>

typedef unsigned short u16;
typedef __attribute__((ext_vector_type(8))) short short8;
typedef __attribute__((ext_vector_type(4))) float f32x4;

constexpr int SEQ   = 2048;
constexpr int HID   = 1024;
constexpr int NHEAD = 16;
constexpr int QKVD  = 1536;   // (16 + 2*4) * 64
constexpr int FFI   = 2816;
constexpr int NEXP  = 8;
constexpr int WINSZ = 512;
#define EPSF 1e-5f

__device__ __forceinline__ u16 f2bf(float f) {
  union { unsigned int i; float f; } v; v.f = f;
  unsigned int i = v.i;
  return (u16)((i + 0x7fffu + ((i >> 16) & 1u)) >> 16);
}

__device__ __forceinline__ ushort4 f2bf4(float4 v) {
  ushort4 o;
  o.x = f2bf(v.x); o.y = f2bf(v.y); o.z = f2bf(v.z); o.w = f2bf(v.w);
  return o;
}

__device__ __forceinline__ void gload_lds16(const void* g, void* l) {
  __builtin_amdgcn_global_load_lds((__attribute__((address_space(1))) void*)g,
                                   (__attribute__((address_space(3))) void*)l,
                                   16, 0, 0);
}

#define MFMA_BF16(a, b, c) __builtin_amdgcn_mfma_f32_16x16x32_bf16(a, b, c, 0, 0, 0)

// one fence per K-tile: drain this tile's prefetch, then barrier
#define TILE_FENCE                                          \
  asm volatile("s_waitcnt vmcnt(0)" ::: "memory");          \
  __builtin_amdgcn_s_barrier();                             \
  __builtin_amdgcn_sched_barrier(0);

// sizes in float4 units (big weights only)
constexpr int CN3 = NEXP * 2 * FFI * HID / 4;  // ws
constexpr int CN4 = NEXP * HID * FFI / 4;      // w2s
constexpr int CN_BIG   = CN3 + CN4;            // 17301504
constexpr int NCONV_BLK = CN_BIG / 1024;       // 16896
constexpr int NATTN_BLK = (SEQ / 64) * NHEAD;  // 512

// ---------------- RMSNorm (f32 in -> bf16 out) ----------------
__global__ __launch_bounds__(256) void k_prep(const float* __restrict__ x,
                                              const float* __restrict__ w,
                                              u16* __restrict__ y) {
  const int bid = blockIdx.x, tid = threadIdx.x;
  const int wid = tid >> 6, lane = tid & 63;
  __shared__ float red[4];
  const float* xr = x + (size_t)bid * HID;
  float4 v = *(const float4*)&xr[tid * 4];
  float ss = v.x * v.x + v.y * v.y + v.z * v.z + v.w * v.w;
#pragma unroll
  for (int m = 1; m < 64; m <<= 1) ss += __shfl_xor(ss, m);
  if (lane == 0) red[wid] = ss;
  __syncthreads();
  ss = red[0] + red[1] + red[2] + red[3];
  float sc = rsqrtf(ss * (1.0f / HID) + EPSF);
  float4 wv = *(const float4*)&w[tid * 4];
  ushort4 o;
  o.x = f2bf(v.x * sc * wv.x);
  o.y = f2bf(v.y * sc * wv.y);
  o.z = f2bf(v.z * sc * wv.z);
  o.w = f2bf(v.w * sc * wv.w);
  *(ushort4*)&y[(size_t)bid * HID + tid * 4] = o;
}

// ---- C = A(MxK,bf16) * B(NxK,f32)^T, 128x64 tile ----
// B is read f32 and converted to bf16 during reg-staged LDS write (pad 72).
// gridDim.z > 1: split-K, f32 plane per z. wf32==0: bf16 out (z must be 1).
__global__ __launch_bounds__(256, 2) void k_gemm_bt(
    const u16* __restrict__ A, const float* __restrict__ B,
    void* __restrict__ Cout, int N, int K, int KT, int wf32) {
  __shared__ u16 As[128 * 64];
  __shared__ u16 Bs[64 * 72];
  const int tid = threadIdx.x, wid = tid >> 6, lane = tid & 63;
  const int quad = lane >> 4, l16 = lane & 15;
  const int wr = wid >> 1, wc = wid & 1;
  const int m0 = blockIdx.y * 128, n0 = blockIdx.x * 64;
  const int M = gridDim.y * 128;
  const int kbase = blockIdx.z * KT * 64;
  const int sr = lane >> 3, sc = (lane & 7) * 8;
  // B staging map: 64 rows x 64 f32; 4 lanes/row, 16 f32 per lane
  const int brow = wid * 16 + (lane >> 2);
  const int bk = (lane & 3) * 16;
  f32x4 acc[4][2] = {};
  for (int kt = 0; kt < KT; ++kt) {
    const int k0 = kbase + (kt << 6);
    const float* bp = &B[(size_t)(n0 + brow) * K + k0 + bk];
    float4 bv0 = *(const float4*)&bp[0];
    float4 bv1 = *(const float4*)&bp[4];
    float4 bv2 = *(const float4*)&bp[8];
    float4 bv3 = *(const float4*)&bp[12];
#pragma unroll
    for (int it = 0; it < 4; ++it) {
      int seg = wid * 4 + it;
      int row = seg * 8 + sr;
      gload_lds16(&A[(size_t)(m0 + row) * K + k0 + sc], &As[seg * 512]);
    }
    *(ushort4*)&Bs[brow * 72 + bk + 0]  = f2bf4(bv0);
    *(ushort4*)&Bs[brow * 72 + bk + 4]  = f2bf4(bv1);
    *(ushort4*)&Bs[brow * 72 + bk + 8]  = f2bf4(bv2);
    *(ushort4*)&Bs[brow * 72 + bk + 12] = f2bf4(bv3);
    __syncthreads();
#pragma unroll
    for (int ks = 0; ks < 2; ++ks) {
      short8 af[4], bf[2];
#pragma unroll
      for (int t = 0; t < 4; ++t)
        af[t] = *(const short8*)&As[(64 * wr + 16 * t + l16) * 64 + ks * 32 + quad * 8];
#pragma unroll
      for (int t = 0; t < 2; ++t)
        bf[t] = *(const short8*)&Bs[(32 * wc + 16 * t + l16) * 72 + ks * 32 + quad * 8];
#pragma unroll
      for (int mt = 0; mt < 4; ++mt)
#pragma unroll
        for (int nt = 0; nt < 2; ++nt)
          acc[mt][nt] = MFMA_BF16(af[mt], bf[nt], acc[mt][nt]);
    }
    __syncthreads();
  }
  if (wf32) {
    float* C = (float*)Cout + (size_t)blockIdx.z * M * N;
#pragma unroll
    for (int mt = 0; mt < 4; ++mt)
#pragma unroll
      for (int r = 0; r < 4; ++r) {
        int row = m0 + 64 * wr + 16 * mt + quad * 4 + r;
#pragma unroll
        for (int nt = 0; nt < 2; ++nt) {
          int col = n0 + 32 * wc + 16 * nt + l16;
          C[(size_t)row * N + col] = acc[mt][nt][r];
        }
      }
  } else {
    u16* C = (u16*)Cout;
#pragma unroll
    for (int mt = 0; mt < 4; ++mt)
#pragma unroll
      for (int r = 0; r < 4; ++r) {
        int row = m0 + 64 * wr + 16 * mt + quad * 4 + r;
#pragma unroll
        for (int nt = 0; nt < 2; ++nt) {
          int col = n0 + 32 * wc + 16 * nt + l16;
          C[(size_t)row * N + col] = f2bf(acc[mt][nt][r]);
        }
      }
  }
}

// ------- sliding-window GQA flash attention + fused big-weight convert ----
__global__ __launch_bounds__(256, 2) void k_attn_conv(
    const u16* __restrict__ qkv, u16* __restrict__ o,
    const float* __restrict__ ws, const float* __restrict__ w2s,
    u16* __restrict__ dws, u16* __restrict__ dw2) {
  const int bid = blockIdx.x;
  const int tid = threadIdx.x;
  if (bid >= NATTN_BLK) {
    int j = (bid - NATTN_BLK) * 1024 + tid;
#pragma unroll
    for (int t = 0; t < 4; ++t) {
      int i = j + t * 256;
      const float* s; u16* d;
      if (i < CN3) { s = ws; d = dws; } else { i -= CN3; s = w2s; d = dw2; }
      float4 v = ((const float4*)s)[i];
      ushort4 u;
      u.x = f2bf(v.x); u.y = f2bf(v.y); u.z = f2bf(v.z); u.w = f2bf(v.w);
      ((ushort4*)d)[i] = u;
    }
    return;
  }
  const int qb = bid & 31;
  const int h  = bid >> 5;
  const int q0 = qb * 64;
  const int g = h >> 2;
  __shared__ u16 Qs[64 * 72], Ks[64 * 72], Vt[64 * 72], Ps[64 * 72];
  const int wid = tid >> 6, lane = tid & 63;
  const int quad = lane >> 4, l16 = lane & 15;

#pragma unroll
  for (int it = 0; it < 2; ++it) {
    int idx = it * 256 + tid;
    int row = idx >> 3, c8 = (idx & 7) * 8;
    *(short8*)&Qs[row * 72 + c8] =
        *(const short8*)&qkv[(size_t)(q0 + row) * QKVD + h * 64 + c8];
  }

  f32x4 oacc[4] = {};
  float mrun[4], lrun[4];
#pragma unroll
  for (int r = 0; r < 4; ++r) { mrun[r] = -1e30f; lrun[r] = 0.f; }

  const int ktlo = (q0 >= WINSZ) ? ((q0 - WINSZ + 1) >> 6) : 0;
  const int kthi = qb;
  for (int kt = ktlo; kt <= kthi; ++kt) {
#pragma unroll
    for (int it = 0; it < 2; ++it) {
      int idx = it * 256 + tid;
      int row = idx >> 3, c8 = (idx & 7) * 8;
      *(short8*)&Ks[row * 72 + c8] =
          *(const short8*)&qkv[(size_t)(kt * 64 + row) * QKVD + 1024 + g * 64 + c8];
    }
#pragma unroll
    for (int it = 0; it < 8; ++it) {
      int idx = it * 256 + tid;
      int key = idx >> 5;
      int d = (idx & 31) * 2;
      unsigned int u = *(const unsigned int*)&qkv[(size_t)(kt * 64 + key) * QKVD + 1280 + g * 64 + d];
      Vt[d * 72 + key] = (u16)(u & 0xffffu);
      Vt[(d + 1) * 72 + key] = (u16)(u >> 16);
    }
    __syncthreads();

    f32x4 sa[4] = {};
#pragma unroll
    for (int ks = 0; ks < 2; ++ks) {
      short8 af = *(const short8*)&Qs[(16 * wid + l16) * 72 + ks * 32 + quad * 8];
#pragma unroll
      for (int ct = 0; ct < 4; ++ct) {
        short8 bf = *(const short8*)&Ks[(16 * ct + l16) * 72 + ks * 32 + quad * 8];
        sa[ct] = MFMA_BF16(af, bf, sa[ct]);
      }
    }

    float pvv[4][4];
#pragma unroll
    for (int r = 0; r < 4; ++r) {
      int i = q0 + 16 * wid + quad * 4 + r;
      float mx = -1e30f;
#pragma unroll
      for (int ct = 0; ct < 4; ++ct) {
        int j = kt * 64 + 16 * ct + l16;
        float v = sa[ct][r] * 0.125f;
        bool ok = (j <= i) && (i - j < WINSZ);
        v = ok ? v : -1e30f;
        pvv[ct][r] = v;
        mx = fmaxf(mx, v);
      }
#pragma unroll
      for (int m = 1; m < 16; m <<= 1) mx = fmaxf(mx, __shfl_xor(mx, m));
      float mnew = fmaxf(mrun[r], mx);
      float alpha = __expf(mrun[r] - mnew);
      float s = 0.f;
#pragma unroll
      for (int ct = 0; ct < 4; ++ct) {
        float p = (pvv[ct][r] > -1e29f) ? __expf(pvv[ct][r] - mnew) : 0.f;
        pvv[ct][r] = p;
        s += p;
      }
#pragma unroll
      for (int m = 1; m < 16; m <<= 1) s += __shfl_xor(s, m);
      lrun[r] = lrun[r] * alpha + s;
      mrun[r] = mnew;
#pragma unroll
      for (int ct = 0; ct < 4; ++ct) oacc[ct][r] *= alpha;
    }
#pragma unroll
    for (int ct = 0; ct < 4; ++ct)
#pragma unroll
      for (int r = 0; r < 4; ++r)
        Ps[(16 * wid + quad * 4 + r) * 72 + 16 * ct + l16] = f2bf(pvv[ct][r]);
    __syncthreads();

#pragma unroll
    for (int ks = 0; ks < 2; ++ks) {
      short8 af = *(const short8*)&Ps[(16 * wid + l16) * 72 + ks * 32 + quad * 8];
#pragma unroll
      for (int ct = 0; ct < 4; ++ct) {
        short8 bf = *(const short8*)&Vt[(16 * ct + l16) * 72 + ks * 32 + quad * 8];
        oacc[ct] = MFMA_BF16(af, bf, oacc[ct]);
      }
    }
    __syncthreads();
  }

#pragma unroll
  for (int ct = 0; ct < 4; ++ct)
#pragma unroll
    for (int r = 0; r < 4; ++r) {
      int row = q0 + 16 * wid + quad * 4 + r;
      float v = oacc[ct][r] / lrun[r];
      o[(size_t)row * HID + h * 64 + 16 * ct + l16] = f2bf(v);
    }
}

// --------- RMSNorm2 + router top-2 (sums O-proj splits + residual) -------
__global__ __launch_bounds__(256) void k_rms2_router(
    const float* __restrict__ o0, const float* __restrict__ o1,
    const float* __restrict__ hs, const float* __restrict__ ln2,
    const float* __restrict__ rw, float* __restrict__ out1,
    u16* __restrict__ T, int* __restrict__ counts,
    int* __restrict__ tok_idx, int* __restrict__ tok_slot,
    float* __restrict__ tok_pw) {
  const int tkn = blockIdx.x, tid = threadIdx.x, wid = tid >> 6, lane = tid & 63;
  const size_t base = (size_t)tkn * HID + tid * 4;
  float4 a = *(const float4*)&o0[base];
  float4 b = *(const float4*)&o1[base];
  float4 h = *(const float4*)&hs[base];
  float4 v;
  v.x = a.x + b.x + h.x; v.y = a.y + b.y + h.y;
  v.z = a.z + b.z + h.z; v.w = a.w + b.w + h.w;
  *(float4*)&out1[base] = v;
  float ss = v.x * v.x + v.y * v.y + v.z * v.z + v.w * v.w;
#pragma unroll
  for (int m = 1; m < 64; m <<= 1) ss += __shfl_xor(ss, m);
  __shared__ float red[4];
  if (lane == 0) red[wid] = ss;
  __syncthreads();
  ss = red[0] + red[1] + red[2] + red[3];
  float sc = rsqrtf(ss * (1.0f / HID) + EPSF);
  float4 lw = *(const float4*)&ln2[tid * 4];
  float t0 = v.x * sc * lw.x;
  float t1 = v.y * sc * lw.y;
  float t2 = v.z * sc * lw.z;
  float t3 = v.w * sc * lw.w;
  ushort4 o;
  o.x = f2bf(t0); o.y = f2bf(t1); o.z = f2bf(t2); o.w = f2bf(t3);
  *(ushort4*)&T[(size_t)tkn * HID + tid * 4] = o;

  float p[8];
#pragma unroll
  for (int e = 0; e < 8; ++e) {
    float4 r = *(const float4*)&rw[e * HID + tid * 4];
    p[e] = t0 * r.x + t1 * r.y + t2 * r.z + t3 * r.w;
  }
#pragma unroll
  for (int e = 0; e < 8; ++e)
#pragma unroll
    for (int m = 1; m < 64; m <<= 1) p[e] += __shfl_xor(p[e], m);
  __shared__ float pr[4][8];
  if (lane == 0)
#pragma unroll
    for (int e = 0; e < 8; ++e) pr[wid][e] = p[e];
  __syncthreads();
  if (tid == 0) {
    float lg[8];
#pragma unroll
    for (int e = 0; e < 8; ++e) lg[e] = pr[0][e] + pr[1][e] + pr[2][e] + pr[3][e];
    float mx = lg[0];
#pragma unroll
    for (int e = 1; e < 8; ++e) mx = fmaxf(mx, lg[e]);
    float ex[8], se = 0.f;
#pragma unroll
    for (int e = 0; e < 8; ++e) { ex[e] = __expf(lg[e] - mx); se += ex[e]; }
    int b0 = 0;
#pragma unroll
    for (int e = 1; e < 8; ++e) if (lg[e] > lg[b0]) b0 = e;
    int b1 = (b0 == 0) ? 1 : 0;
#pragma unroll
    for (int e = 0; e < 8; ++e) if (e != b0 && lg[e] > lg[b1]) b1 = e;
    float inv = 1.0f / se;
    int s0 = atomicAdd(&counts[b0], 1);
    tok_idx[b0 * SEQ + s0] = tkn;
    tok_slot[2 * tkn] = b0 * SEQ + s0;
    tok_pw[2 * tkn] = ex[b0] * inv;
    int s1 = atomicAdd(&counts[b1], 1);
    tok_idx[b1 * SEQ + s1] = tkn;
    tok_slot[2 * tkn + 1] = b1 * SEQ + s1;
    tok_pw[2 * tkn + 1] = ex[b1] * inv;
  }
}

__global__ void k_offsets(const int* __restrict__ counts, int* __restrict__ offs) {
  if (threadIdx.x == 0 && blockIdx.x == 0) {
    int s = 0;
    for (int e = 0; e < NEXP; ++e) { offs[e] = s; s += counts[e]; }
    offs[NEXP] = s;
  }
}

// -- MoE up GEMM: 256m x (128g + 128u), 8 waves, dbuf, 1 barrier/tile --
__global__ __launch_bounds__(512, 2) void k_moe_gu(
    const u16* __restrict__ T, const u16* __restrict__ Wgu,
    const int* __restrict__ counts, const int* __restrict__ offs,
    const int* __restrict__ tok_idx, u16* __restrict__ Abuf) {
  const int e = blockIdx.z;
  const int cnt = counts[e];
  const int m0 = blockIdx.y * 256;
  if (m0 >= cnt) return;
  const int n0 = blockIdx.x * 128;
  const u16* We = Wgu + (size_t)e * 2 * FFI * HID;
  const int* ti = tok_idx + e * SEQ;
  const int aoff = offs[e];
  __shared__ u16 As[2][256 * 64], Bg[2][128 * 64], Bu[2][128 * 64];  // 128 KiB
  const int tid = threadIdx.x, wid = tid >> 6, lane = tid & 63;
  const int quad = lane >> 4, l16 = lane & 15;
  const int wr = wid >> 2, wc = wid & 3;  // wave: 128m x 32n (of g and u)
  const int sr = lane >> 3, sc = (lane & 7) * 8;
  int tokrow[4];
#pragma unroll
  for (int it = 0; it < 4; ++it) {
    int row = (wid * 4 + it) * 8 + sr;   // seg 0..31 -> rows 0..255
    int ra = m0 + row;
    if (ra > cnt - 1) ra = cnt - 1;
    tokrow[it] = ti[ra];
  }
  f32x4 accg[8][2] = {}, accu[8][2] = {};

#define MSTAGE(buf, k0)                                                              \
  {                                                                                  \
    _Pragma("unroll") for (int it = 0; it < 4; ++it) {                               \
      int seg = wid * 4 + it;                                                        \
      gload_lds16(&T[(size_t)tokrow[it] * HID + (k0) + sc], &As[buf][seg * 512]);    \
    }                                                                                \
    _Pragma("unroll") for (int it = 0; it < 2; ++it) {                               \
      int seg = wid * 2 + it;                                                        \
      int row = seg * 8 + sr;                                                        \
      gload_lds16(&We[(size_t)(n0 + row) * HID + (k0) + sc], &Bg[buf][seg * 512]);   \
      gload_lds16(&We[(size_t)(FFI + n0 + row) * HID + (k0) + sc],                   \
                  &Bu[buf][seg * 512]);                                              \
    }                                                                                \
  }
#define MCOMP(buf)                                                                   \
  {                                                                                  \
    _Pragma("unroll") for (int ks = 0; ks < 2; ++ks) {                               \
      short8 af[8], bg[2], bu[2];                                                    \
      _Pragma("unroll") for (int t = 0; t < 8; ++t)                                  \
        af[t] = *(const short8*)&As[buf][(128 * wr + 16 * t + l16) * 64 + ks * 32 +  \
                                         quad * 8];                                  \
      _Pragma("unroll") for (int t = 0; t < 2; ++t) {                                \
        bg[t] = *(const short8*)&Bg[buf][(32 * wc + 16 * t + l16) * 64 + ks * 32 +   \
                                         quad * 8];                                  \
        bu[t] = *(const short8*)&Bu[buf][(32 * wc + 16 * t + l16) * 64 + ks * 32 +   \
                                         quad * 8];                                  \
      }                                                                              \
      _Pragma("unroll") for (int mt = 0; mt < 8; ++mt)                               \
        _Pragma("unroll") for (int nt = 0; nt < 2; ++nt) {                           \
          accg[mt][nt] = MFMA_BF16(af[mt], bg[nt], accg[mt][nt]);                    \
          accu[mt][nt] = MFMA_BF16(af[mt], bu[nt], accu[mt][nt]);                    \
        }                                                                            \
    }                                                                                \
  }

  MSTAGE(0, 0);
  TILE_FENCE
  int cur = 0;
  for (int kt = 0; kt < 16; ++kt) {
    if (kt + 1 < 16) MSTAGE(cur ^ 1, (kt + 1) << 6);
    MCOMP(cur);
    if (kt + 1 < 16) { TILE_FENCE }
    cur ^= 1;
  }
#undef MSTAGE
#undef MCOMP
#pragma unroll
  for (int mt = 0; mt < 8; ++mt)
#pragma unroll
    for (int r = 0; r < 4; ++r) {
      int rl = 128 * wr + 16 * mt + quad * 4 + r;
      int grow = m0 + rl;
      if (grow < cnt) {
        size_t rbase = (size_t)(aoff + grow) * FFI;
#pragma unroll
        for (int nt = 0; nt < 2; ++nt) {
          int col = n0 + 32 * wc + 16 * nt + l16;
          float gv = accg[mt][nt][r];
          float uv = accu[mt][nt][r];
          float a = gv / (1.0f + __expf(-gv)) * uv;
          Abuf[rbase + col] = f2bf(a);
        }
      }
    }
}

// -- MoE down GEMM: 128m x 256n, split-K x2, 8 waves, dbuf, 1 barrier/tile --
__global__ __launch_bounds__(512, 2) void k_moe_y(
    const u16* __restrict__ Abuf, const u16* __restrict__ W2,
    const int* __restrict__ counts, const int* __restrict__ offs,
    float* __restrict__ ybuf) {
  const int e = blockIdx.z >> 1;
  const int sk = blockIdx.z & 1;
  const int cnt = counts[e];
  const int m0 = blockIdx.y * 128;
  if (m0 >= cnt) return;
  const int n0 = blockIdx.x * 256;
  const int kbase = sk * 1408;  // 2816 / 2
  const u16* We = W2 + (size_t)e * HID * FFI;
  const int aoff = offs[e];
  __shared__ u16 As[2][128 * 64], Bs[2][256 * 64];  // 96 KiB
  const int tid = threadIdx.x, wid = tid >> 6, lane = tid & 63;
  const int quad = lane >> 4, l16 = lane & 15;
  const int wr = wid >> 2, wc = wid & 3;  // wave: 64m x 64n
  const int sr = lane >> 3, sc = (lane & 7) * 8;
  int arow[2];
#pragma unroll
  for (int it = 0; it < 2; ++it) {
    int row = (wid * 2 + it) * 8 + sr;   // seg 0..15 -> rows 0..127
    int ra = m0 + row;
    if (ra > cnt - 1) ra = cnt - 1;
    arow[it] = aoff + ra;
  }
  f32x4 acc[4][4] = {};

#define YSTAGE(buf, k0)                                                              \
  {                                                                                  \
    _Pragma("unroll") for (int it = 0; it < 2; ++it) {                               \
      int seg = wid * 2 + it;                                                        \
      gload_lds16(&Abuf[(size_t)arow[it] * FFI + (k0) + sc], &As[buf][seg * 512]);   \
    }                                                                                \
    _Pragma("unroll") for (int it = 0; it < 4; ++it) {                               \
      int seg = wid * 4 + it;                                                        \
      int row = seg * 8 + sr;                                                        \
      gload_lds16(&We[(size_t)(n0 + row) * FFI + (k0) + sc], &Bs[buf][seg * 512]);   \
    }                                                                                \
  }
#define YCOMP(buf)                                                                   \
  {                                                                                  \
    _Pragma("unroll") for (int ks = 0; ks < 2; ++ks) {                               \
      short8 af[4], bf[4];                                                           \
      _Pragma("unroll") for (int t = 0; t < 4; ++t)                                  \
        af[t] = *(const short8*)&As[buf][(64 * wr + 16 * t + l16) * 64 + ks * 32 +   \
                                         quad * 8];                                  \
      _Pragma("unroll") for (int t = 0; t < 4; ++t)                                  \
        bf[t] = *(const short8*)&Bs[buf][(64 * wc + 16 * t + l16) * 64 + ks * 32 +   \
                                         quad * 8];                                  \
      _Pragma("unroll") for (int mt = 0; mt < 4; ++mt)                               \
        _Pragma("unroll") for (int nt = 0; nt < 4; ++nt)                             \
            acc[mt][nt] = MFMA_BF16(af[mt], bf[nt], acc[mt][nt]);                    \
    }                                                                                \
  }

  YSTAGE(0, kbase);
  TILE_FENCE
  int cur = 0;
  for (int kt = 0; kt < 22; ++kt) {
    if (kt + 1 < 22) YSTAGE(cur ^ 1, kbase + ((kt + 1) << 6));
    YCOMP(cur);
    if (kt + 1 < 22) { TILE_FENCE }
    cur ^= 1;
  }
#undef YSTAGE
#undef YCOMP
  float* Y = ybuf + (size_t)sk * 2 * SEQ * HID;
#pragma unroll
  for (int mt = 0; mt < 4; ++mt)
#pragma unroll
    for (int r = 0; r < 4; ++r) {
      int rl = 64 * wr + 16 * mt + quad * 4 + r;
      int grow = m0 + rl;
      if (grow < cnt) {
        size_t obase = (size_t)(aoff + grow) * HID;
#pragma unroll
        for (int nt = 0; nt < 4; ++nt) {
          int col = n0 + 64 * wc + 16 * nt + l16;
          Y[obase + col] = acc[mt][nt][r];
        }
      }
    }
}

// ---- final gather: out[t] = w0*(y0[s0]+y1[s0]) + w1*(y0[s1]+y1[s1]) ----
__global__ __launch_bounds__(256) void k_moe_out(
    const float* __restrict__ yb, const int* __restrict__ offs,
    const int* __restrict__ tok_slot, const float* __restrict__ tok_pw,
    float* __restrict__ out0) {
  const int t = blockIdx.x, tid = threadIdx.x;
  const int v0 = tok_slot[2 * t], v1 = tok_slot[2 * t + 1];
  const float w0 = tok_pw[2 * t], w1 = tok_pw[2 * t + 1];
  const size_t g0 = (size_t)(offs[v0 >> 11] + (v0 & (SEQ - 1))) * HID;
  const size_t g1 = (size_t)(offs[v1 >> 11] + (v1 & (SEQ - 1))) * HID;
  const size_t YP = (size_t)2 * SEQ * HID;
  const int c = tid * 4;
  float4 a0 = *(const float4*)&yb[g0 + c];
  float4 b0 = *(const float4*)&yb[YP + g0 + c];
  float4 a1 = *(const float4*)&yb[g1 + c];
  float4 b1 = *(const float4*)&yb[YP + g1 + c];
  float4 r;
  r.x = w0 * (a0.x + b0.x) + w1 * (a1.x + b1.x);
  r.y = w0 * (a0.y + b0.y) + w1 * (a1.y + b1.y);
  r.z = w0 * (a0.z + b0.z) + w1 * (a1.z + b1.z);
  r.w = w0 * (a0.w + b0.w) + w1 * (a1.w + b1.w);
  *(float4*)&out0[(size_t)t * HID + c] = r;
}

extern "C" void kernel_launch(void* const* d_in, const int* in_sizes, int n_in,
                              void* d_out, int out_size, void* d_ws, size_t ws_size,
                              hipStream_t stream) {
  const float* hs   = (const float*)d_in[0];
  const float* wqkv = (const float*)d_in[2];
  const float* wo   = (const float*)d_in[3];
  const float* rwt  = (const float*)d_in[4];
  const float* wsx  = (const float*)d_in[5];
  const float* w2s  = (const float*)d_in[6];
  const float* ln1  = (const float*)d_in[7];
  const float* ln2  = (const float*)d_in[8];
  float* out0 = (float*)d_out;                       // MoE output (f32)
  float* out1 = out0 + (size_t)SEQ * HID;            // residual2 (f32)

  char* p = (char*)d_ws;
  u16* xn       = (u16*)p;   p += (size_t)SEQ * HID * 2;
  u16* qkv      = (u16*)p;   p += (size_t)SEQ * QKVD * 2;
  u16* ob       = (u16*)p;   p += (size_t)SEQ * HID * 2;
  float* of     = (float*)p; p += (size_t)2 * SEQ * HID * 4;  // 2 split planes
  int* counts   = (int*)p;   p += 32;
  int* offs     = (int*)p;   p += 64;
  int* tok_idx  = (int*)p;   p += (size_t)NEXP * SEQ * 4;
  int* tok_slot = (int*)p;   p += (size_t)2 * SEQ * 4;
  float* tok_pw = (float*)p; p += (size_t)2 * SEQ * 4;
  u16* abuf     = (u16*)p;   p += (size_t)2 * SEQ * FFI * 2;
  float* ybuf   = (float*)p; p += (size_t)2 * 2 * SEQ * HID * 4;  // 2 sk planes
  u16* ws_b     = (u16*)p;   p += (size_t)NEXP * 2 * FFI * HID * 2;
  u16* w2s_b    = (u16*)p;   p += (size_t)NEXP * HID * FFI * 2;

  u16* tb = xn;  // alias: xn dead after QKV GEMM

  hipMemsetAsync(counts, 0, 32, stream);

  k_prep<<<SEQ, 256, 0, stream>>>(hs, ln1, xn);
  // QKV: M=2048, N=1536, K=1024, full-K, bf16 epilogue (B = f32 wqkv direct)
  k_gemm_bt<<<dim3(QKVD / 64, SEQ / 128, 1), 256, 0, stream>>>(
      xn, wqkv, qkv, QKVD, HID, 16, 0);
  // attention + fused ws/w2s conversion
  k_attn_conv<<<NATTN_BLK + NCONV_BLK, 256, 0, stream>>>(
      qkv, ob, wsx, w2s, ws_b, w2s_b);
  // O-proj: M=2048, N=1024, K=1024, split-K x2 (B = f32 wo direct)
  k_gemm_bt<<<dim3(HID / 64, SEQ / 128, 2), 256, 0, stream>>>(
      ob, wo, of, HID, HID, 8, 1);
  k_rms2_router<<<SEQ, 256, 0, stream>>>(of, of + (size_t)SEQ * HID, hs, ln2,
                                         rwt, out1, tb, counts, tok_idx,
                                         tok_slot, tok_pw);
  k_offsets<<<1, 64, 0, stream>>>(counts, offs);
  k_moe_gu<<<dim3(FFI / 128, SEQ / 256, NEXP), 512, 0, stream>>>(
      tb, ws_b, counts, offs, tok_idx, abuf);
  k_moe_y<<<dim3(HID / 256, SEQ / 128, NEXP * 2), 512, 0, stream>>>(
      abuf, w2s_b, counts, offs, ybuf);
  k_moe_out<<<SEQ, 256, 0, stream>>>(ybuf, offs, tok_slot, tok_pw, out0);
}

// Round 6
// 637.349 us; speedup vs baseline: 1.0784x; 1.0638x over previous
//
#include <hip/hip_runtime.h>
#include <stdint.h>

typedef unsigned short u16;
typedef __attribute__((ext_vector_type(8))) short short8;
typedef __attribute__((ext_vector_type(4))) float f32x4;

constexpr int SEQ   = 2048;
constexpr int HID   = 1024;
constexpr int NHEAD = 16;
constexpr int QKVD  = 1536;   // (16 + 2*4) * 64
constexpr int FFI   = 2816;
constexpr int NEXP  = 8;
constexpr int WINSZ = 512;
#define EPSF 1e-5f

__device__ __forceinline__ u16 f2bf(float f) {
  union { unsigned int i; float f; } v; v.f = f;
  unsigned int i = v.i;
  return (u16)((i + 0x7fffu + ((i >> 16) & 1u)) >> 16);
}

__device__ __forceinline__ ushort4 f2bf4(float4 v) {
  ushort4 o;
  o.x = f2bf(v.x); o.y = f2bf(v.y); o.z = f2bf(v.z); o.w = f2bf(v.w);
  return o;
}

__device__ __forceinline__ void gload_lds16(const void* g, void* l) {
  __builtin_amdgcn_global_load_lds((__attribute__((address_space(1))) void*)g,
                                   (__attribute__((address_space(3))) void*)l,
                                   16, 0, 0);
}

#define MFMA_BF16(a, b, c) __builtin_amdgcn_mfma_f32_16x16x32_bf16(a, b, c, 0, 0, 0)

#define SBAR  __builtin_amdgcn_s_barrier()
#define SCHB  __builtin_amdgcn_sched_barrier(0)

// sizes in float4 units (big weights only)
constexpr int CN3 = NEXP * 2 * FFI * HID / 4;  // ws
constexpr int CN4 = NEXP * HID * FFI / 4;      // w2s
constexpr int CN_BIG   = CN3 + CN4;            // 17301504
constexpr int NCONV_BLK = CN_BIG / 1024;       // 16896
constexpr int NATTN_BLK = (SEQ / 64) * NHEAD;  // 512

// ---------------- RMSNorm (f32 in -> bf16 out) ----------------
__global__ __launch_bounds__(256) void k_prep(const float* __restrict__ x,
                                              const float* __restrict__ w,
                                              u16* __restrict__ y) {
  const int bid = blockIdx.x, tid = threadIdx.x;
  const int wid = tid >> 6, lane = tid & 63;
  __shared__ float red[4];
  const float* xr = x + (size_t)bid * HID;
  float4 v = *(const float4*)&xr[tid * 4];
  float ss = v.x * v.x + v.y * v.y + v.z * v.z + v.w * v.w;
#pragma unroll
  for (int m = 1; m < 64; m <<= 1) ss += __shfl_xor(ss, m);
  if (lane == 0) red[wid] = ss;
  __syncthreads();
  ss = red[0] + red[1] + red[2] + red[3];
  float sc = rsqrtf(ss * (1.0f / HID) + EPSF);
  float4 wv = *(const float4*)&w[tid * 4];
  ushort4 o;
  o.x = f2bf(v.x * sc * wv.x);
  o.y = f2bf(v.y * sc * wv.y);
  o.z = f2bf(v.z * sc * wv.z);
  o.w = f2bf(v.w * sc * wv.w);
  *(ushort4*)&y[(size_t)bid * HID + tid * 4] = o;
}

// ---- C = A(MxK,bf16) * B(NxK,f32)^T, 128x64 tile ----
// A staged via gload_lds with XOR-swizzled SOURCE column; reads XOR-match.
// B read f32, reg-converted to bf16, pad-72 LDS (conflict-free already).
__global__ __launch_bounds__(256, 2) void k_gemm_bt(
    const u16* __restrict__ A, const float* __restrict__ B,
    void* __restrict__ Cout, int N, int K, int KT, int wf32) {
  __shared__ u16 As[128 * 64];
  __shared__ u16 Bs[64 * 72];
  const int tid = threadIdx.x, wid = tid >> 6, lane = tid & 63;
  const int quad = lane >> 4, l16 = lane & 15;
  const int wr = wid >> 1, wc = wid & 1;
  const int m0 = blockIdx.y * 128, n0 = blockIdx.x * 64;
  const int M = gridDim.y * 128;
  const int kbase = blockIdx.z * KT * 64;
  const int sr = lane >> 3;
  const int scs = (((lane & 7) ^ sr) * 8);   // swizzled source col (elems)
  const int rx = l16 & 7;                    // read-side row parity
  // B staging map: 64 rows x 64 f32; 4 lanes/row, 16 f32 per lane
  const int brow = wid * 16 + (lane >> 2);
  const int bk = (lane & 3) * 16;
  f32x4 acc[4][2] = {};
  for (int kt = 0; kt < KT; ++kt) {
    const int k0 = kbase + (kt << 6);
    const float* bp = &B[(size_t)(n0 + brow) * K + k0 + bk];
    float4 bv0 = *(const float4*)&bp[0];
    float4 bv1 = *(const float4*)&bp[4];
    float4 bv2 = *(const float4*)&bp[8];
    float4 bv3 = *(const float4*)&bp[12];
#pragma unroll
    for (int it = 0; it < 4; ++it) {
      int seg = wid * 4 + it;
      int row = seg * 8 + sr;
      gload_lds16(&A[(size_t)(m0 + row) * K + k0 + scs], &As[seg * 512]);
    }
    *(ushort4*)&Bs[brow * 72 + bk + 0]  = f2bf4(bv0);
    *(ushort4*)&Bs[brow * 72 + bk + 4]  = f2bf4(bv1);
    *(ushort4*)&Bs[brow * 72 + bk + 8]  = f2bf4(bv2);
    *(ushort4*)&Bs[brow * 72 + bk + 12] = f2bf4(bv3);
    __syncthreads();
#pragma unroll
    for (int ks = 0; ks < 2; ++ks) {
      const int cof = ((((ks << 2) | quad) ^ rx) << 3);
      short8 af[4], bf[2];
#pragma unroll
      for (int t = 0; t < 4; ++t)
        af[t] = *(const short8*)&As[(64 * wr + 16 * t + l16) * 64 + cof];
#pragma unroll
      for (int t = 0; t < 2; ++t)
        bf[t] = *(const short8*)&Bs[(32 * wc + 16 * t + l16) * 72 + ks * 32 + quad * 8];
#pragma unroll
      for (int mt = 0; mt < 4; ++mt)
#pragma unroll
        for (int nt = 0; nt < 2; ++nt)
          acc[mt][nt] = MFMA_BF16(af[mt], bf[nt], acc[mt][nt]);
    }
    __syncthreads();
  }
  if (wf32) {
    float* C = (float*)Cout + (size_t)blockIdx.z * M * N;
#pragma unroll
    for (int mt = 0; mt < 4; ++mt)
#pragma unroll
      for (int r = 0; r < 4; ++r) {
        int row = m0 + 64 * wr + 16 * mt + quad * 4 + r;
#pragma unroll
        for (int nt = 0; nt < 2; ++nt) {
          int col = n0 + 32 * wc + 16 * nt + l16;
          C[(size_t)row * N + col] = acc[mt][nt][r];
        }
      }
  } else {
    u16* C = (u16*)Cout;
#pragma unroll
    for (int mt = 0; mt < 4; ++mt)
#pragma unroll
      for (int r = 0; r < 4; ++r) {
        int row = m0 + 64 * wr + 16 * mt + quad * 4 + r;
#pragma unroll
        for (int nt = 0; nt < 2; ++nt) {
          int col = n0 + 32 * wc + 16 * nt + l16;
          C[(size_t)row * N + col] = f2bf(acc[mt][nt][r]);
        }
      }
  }
}

// ------- sliding-window GQA flash attention + fused big-weight convert ----
__global__ __launch_bounds__(256, 2) void k_attn_conv(
    const u16* __restrict__ qkv, u16* __restrict__ o,
    const float* __restrict__ ws, const float* __restrict__ w2s,
    u16* __restrict__ dws, u16* __restrict__ dw2) {
  const int bid = blockIdx.x;
  const int tid = threadIdx.x;
  if (bid >= NATTN_BLK) {
    int j = (bid - NATTN_BLK) * 1024 + tid;
#pragma unroll
    for (int t = 0; t < 4; ++t) {
      int i = j + t * 256;
      const float* s; u16* d;
      if (i < CN3) { s = ws; d = dws; } else { i -= CN3; s = w2s; d = dw2; }
      float4 v = ((const float4*)s)[i];
      ushort4 u;
      u.x = f2bf(v.x); u.y = f2bf(v.y); u.z = f2bf(v.z); u.w = f2bf(v.w);
      ((ushort4*)d)[i] = u;
    }
    return;
  }
  const int qb = bid & 31;
  const int h  = bid >> 5;
  const int q0 = qb * 64;
  const int g = h >> 2;
  __shared__ u16 Qs[64 * 72], Ks[64 * 72], Vt[64 * 72], Ps[64 * 72];
  const int wid = tid >> 6, lane = tid & 63;
  const int quad = lane >> 4, l16 = lane & 15;

#pragma unroll
  for (int it = 0; it < 2; ++it) {
    int idx = it * 256 + tid;
    int row = idx >> 3, c8 = (idx & 7) * 8;
    *(short8*)&Qs[row * 72 + c8] =
        *(const short8*)&qkv[(size_t)(q0 + row) * QKVD + h * 64 + c8];
  }

  f32x4 oacc[4] = {};
  float mrun[4], lrun[4];
#pragma unroll
  for (int r = 0; r < 4; ++r) { mrun[r] = -1e30f; lrun[r] = 0.f; }

  const int ktlo = (q0 >= WINSZ) ? ((q0 - WINSZ + 1) >> 6) : 0;
  const int kthi = qb;
  for (int kt = ktlo; kt <= kthi; ++kt) {
#pragma unroll
    for (int it = 0; it < 2; ++it) {
      int idx = it * 256 + tid;
      int row = idx >> 3, c8 = (idx & 7) * 8;
      *(short8*)&Ks[row * 72 + c8] =
          *(const short8*)&qkv[(size_t)(kt * 64 + row) * QKVD + 1024 + g * 64 + c8];
    }
#pragma unroll
    for (int it = 0; it < 8; ++it) {
      int idx = it * 256 + tid;
      int key = idx >> 5;
      int d = (idx & 31) * 2;
      unsigned int u = *(const unsigned int*)&qkv[(size_t)(kt * 64 + key) * QKVD + 1280 + g * 64 + d];
      Vt[d * 72 + key] = (u16)(u & 0xffffu);
      Vt[(d + 1) * 72 + key] = (u16)(u >> 16);
    }
    __syncthreads();

    f32x4 sa[4] = {};
#pragma unroll
    for (int ks = 0; ks < 2; ++ks) {
      short8 af = *(const short8*)&Qs[(16 * wid + l16) * 72 + ks * 32 + quad * 8];
#pragma unroll
      for (int ct = 0; ct < 4; ++ct) {
        short8 bf = *(const short8*)&Ks[(16 * ct + l16) * 72 + ks * 32 + quad * 8];
        sa[ct] = MFMA_BF16(af, bf, sa[ct]);
      }
    }

    float pvv[4][4];
#pragma unroll
    for (int r = 0; r < 4; ++r) {
      int i = q0 + 16 * wid + quad * 4 + r;
      float mx = -1e30f;
#pragma unroll
      for (int ct = 0; ct < 4; ++ct) {
        int j = kt * 64 + 16 * ct + l16;
        float v = sa[ct][r] * 0.125f;
        bool ok = (j <= i) && (i - j < WINSZ);
        v = ok ? v : -1e30f;
        pvv[ct][r] = v;
        mx = fmaxf(mx, v);
      }
#pragma unroll
      for (int m = 1; m < 16; m <<= 1) mx = fmaxf(mx, __shfl_xor(mx, m));
      float mnew = fmaxf(mrun[r], mx);
      float alpha = __expf(mrun[r] - mnew);
      float s = 0.f;
#pragma unroll
      for (int ct = 0; ct < 4; ++ct) {
        float p = (pvv[ct][r] > -1e29f) ? __expf(pvv[ct][r] - mnew) : 0.f;
        pvv[ct][r] = p;
        s += p;
      }
#pragma unroll
      for (int m = 1; m < 16; m <<= 1) s += __shfl_xor(s, m);
      lrun[r] = lrun[r] * alpha + s;
      mrun[r] = mnew;
#pragma unroll
      for (int ct = 0; ct < 4; ++ct) oacc[ct][r] *= alpha;
    }
#pragma unroll
    for (int ct = 0; ct < 4; ++ct)
#pragma unroll
      for (int r = 0; r < 4; ++r)
        Ps[(16 * wid + quad * 4 + r) * 72 + 16 * ct + l16] = f2bf(pvv[ct][r]);
    __syncthreads();

#pragma unroll
    for (int ks = 0; ks < 2; ++ks) {
      short8 af = *(const short8*)&Ps[(16 * wid + l16) * 72 + ks * 32 + quad * 8];
#pragma unroll
      for (int ct = 0; ct < 4; ++ct) {
        short8 bf = *(const short8*)&Vt[(16 * ct + l16) * 72 + ks * 32 + quad * 8];
        oacc[ct] = MFMA_BF16(af, bf, oacc[ct]);
      }
    }
    __syncthreads();
  }

#pragma unroll
  for (int ct = 0; ct < 4; ++ct)
#pragma unroll
    for (int r = 0; r < 4; ++r) {
      int row = q0 + 16 * wid + quad * 4 + r;
      float v = oacc[ct][r] / lrun[r];
      o[(size_t)row * HID + h * 64 + 16 * ct + l16] = f2bf(v);
    }
}

// --------- RMSNorm2 + router top-2 (sums O-proj splits + residual) -------
__global__ __launch_bounds__(256) void k_rms2_router(
    const float* __restrict__ o0, const float* __restrict__ o1,
    const float* __restrict__ hs, const float* __restrict__ ln2,
    const float* __restrict__ rw, float* __restrict__ out1,
    u16* __restrict__ T, int* __restrict__ counts,
    int* __restrict__ tok_idx, int* __restrict__ tok_slot,
    float* __restrict__ tok_pw) {
  const int tkn = blockIdx.x, tid = threadIdx.x, wid = tid >> 6, lane = tid & 63;
  const size_t base = (size_t)tkn * HID + tid * 4;
  float4 a = *(const float4*)&o0[base];
  float4 b = *(const float4*)&o1[base];
  float4 h = *(const float4*)&hs[base];
  float4 v;
  v.x = a.x + b.x + h.x; v.y = a.y + b.y + h.y;
  v.z = a.z + b.z + h.z; v.w = a.w + b.w + h.w;
  *(float4*)&out1[base] = v;
  float ss = v.x * v.x + v.y * v.y + v.z * v.z + v.w * v.w;
#pragma unroll
  for (int m = 1; m < 64; m <<= 1) ss += __shfl_xor(ss, m);
  __shared__ float red[4];
  if (lane == 0) red[wid] = ss;
  __syncthreads();
  ss = red[0] + red[1] + red[2] + red[3];
  float sc = rsqrtf(ss * (1.0f / HID) + EPSF);
  float4 lw = *(const float4*)&ln2[tid * 4];
  float t0 = v.x * sc * lw.x;
  float t1 = v.y * sc * lw.y;
  float t2 = v.z * sc * lw.z;
  float t3 = v.w * sc * lw.w;
  ushort4 o;
  o.x = f2bf(t0); o.y = f2bf(t1); o.z = f2bf(t2); o.w = f2bf(t3);
  *(ushort4*)&T[(size_t)tkn * HID + tid * 4] = o;

  float p[8];
#pragma unroll
  for (int e = 0; e < 8; ++e) {
    float4 r = *(const float4*)&rw[e * HID + tid * 4];
    p[e] = t0 * r.x + t1 * r.y + t2 * r.z + t3 * r.w;
  }
#pragma unroll
  for (int e = 0; e < 8; ++e)
#pragma unroll
    for (int m = 1; m < 64; m <<= 1) p[e] += __shfl_xor(p[e], m);
  __shared__ float pr[4][8];
  if (lane == 0)
#pragma unroll
    for (int e = 0; e < 8; ++e) pr[wid][e] = p[e];
  __syncthreads();
  if (tid == 0) {
    float lg[8];
#pragma unroll
    for (int e = 0; e < 8; ++e) lg[e] = pr[0][e] + pr[1][e] + pr[2][e] + pr[3][e];
    float mx = lg[0];
#pragma unroll
    for (int e = 1; e < 8; ++e) mx = fmaxf(mx, lg[e]);
    float ex[8], se = 0.f;
#pragma unroll
    for (int e = 0; e < 8; ++e) { ex[e] = __expf(lg[e] - mx); se += ex[e]; }
    int b0 = 0;
#pragma unroll
    for (int e = 1; e < 8; ++e) if (lg[e] > lg[b0]) b0 = e;
    int b1 = (b0 == 0) ? 1 : 0;
#pragma unroll
    for (int e = 0; e < 8; ++e) if (e != b0 && lg[e] > lg[b1]) b1 = e;
    float inv = 1.0f / se;
    int s0 = atomicAdd(&counts[b0], 1);
    tok_idx[b0 * SEQ + s0] = tkn;
    tok_slot[2 * tkn] = b0 * SEQ + s0;
    tok_pw[2 * tkn] = ex[b0] * inv;
    int s1 = atomicAdd(&counts[b1], 1);
    tok_idx[b1 * SEQ + s1] = tkn;
    tok_slot[2 * tkn + 1] = b1 * SEQ + s1;
    tok_pw[2 * tkn + 1] = ex[b1] * inv;
  }
}

__global__ void k_offsets(const int* __restrict__ counts, int* __restrict__ offs) {
  if (threadIdx.x == 0 && blockIdx.x == 0) {
    int s = 0;
    for (int e = 0; e < NEXP; ++e) { offs[e] = s; s += counts[e]; }
    offs[NEXP] = s;
  }
}

// -- MoE up GEMM: 256m x (128g + 128u), 8 waves, depth-2 counted pipeline --
// LDS tiles XOR-swizzled (source-side) for conflict-free ds_read_b128.
__global__ __launch_bounds__(512, 2) void k_moe_gu(
    const u16* __restrict__ T, const u16* __restrict__ Wgu,
    const int* __restrict__ counts, const int* __restrict__ offs,
    const int* __restrict__ tok_idx, u16* __restrict__ Abuf) {
  const int e = blockIdx.z;
  const int cnt = counts[e];
  const int m0 = blockIdx.y * 256;
  if (m0 >= cnt) return;
  const int n0 = blockIdx.x * 128;
  const u16* We = Wgu + (size_t)e * 2 * FFI * HID;
  const int* ti = tok_idx + e * SEQ;
  const int aoff = offs[e];
  __shared__ u16 As[2][256 * 64], Bg[2][128 * 64], Bu[2][128 * 64];  // 128 KiB
  const int tid = threadIdx.x, wid = tid >> 6, lane = tid & 63;
  const int quad = lane >> 4, l16 = lane & 15;
  const int wr = wid >> 2, wc = wid & 3;  // wave: 128m x 32n (of g and u)
  const int sr = lane >> 3;
  const int scs = (((lane & 7) ^ sr) * 8);  // swizzled source col
  const int rx = l16 & 7;
  int tokrow[4];
#pragma unroll
  for (int it = 0; it < 4; ++it) {
    int row = (wid * 4 + it) * 8 + sr;   // seg 0..31 -> rows 0..255
    int ra = m0 + row;
    if (ra > cnt - 1) ra = cnt - 1;
    tokrow[it] = ti[ra];
  }
  f32x4 accg[8][2] = {}, accu[8][2] = {};

  // 8 gload_lds per wave per tile
#define MSTAGE(buf, k0)                                                              \
  {                                                                                  \
    _Pragma("unroll") for (int it = 0; it < 4; ++it) {                               \
      int seg = wid * 4 + it;                                                        \
      gload_lds16(&T[(size_t)tokrow[it] * HID + (k0) + scs], &As[buf][seg * 512]);   \
    }                                                                                \
    _Pragma("unroll") for (int it = 0; it < 2; ++it) {                               \
      int seg = wid * 2 + it;                                                        \
      int row = seg * 8 + sr;                                                        \
      gload_lds16(&We[(size_t)(n0 + row) * HID + (k0) + scs], &Bg[buf][seg * 512]);  \
      gload_lds16(&We[(size_t)(FFI + n0 + row) * HID + (k0) + scs],                  \
                  &Bu[buf][seg * 512]);                                              \
    }                                                                                \
  }
#define MCOMP(buf)                                                                   \
  {                                                                                  \
    _Pragma("unroll") for (int ks = 0; ks < 2; ++ks) {                               \
      const int cof = ((((ks << 2) | quad) ^ rx) << 3);                              \
      short8 af[8], bg[2], bu[2];                                                    \
      _Pragma("unroll") for (int t = 0; t < 8; ++t)                                  \
        af[t] = *(const short8*)&As[buf][(128 * wr + 16 * t + l16) * 64 + cof];      \
      _Pragma("unroll") for (int t = 0; t < 2; ++t) {                                \
        bg[t] = *(const short8*)&Bg[buf][(32 * wc + 16 * t + l16) * 64 + cof];       \
        bu[t] = *(const short8*)&Bu[buf][(32 * wc + 16 * t + l16) * 64 + cof];       \
      }                                                                              \
      _Pragma("unroll") for (int mt = 0; mt < 8; ++mt)                               \
        _Pragma("unroll") for (int nt = 0; nt < 2; ++nt) {                           \
          accg[mt][nt] = MFMA_BF16(af[mt], bg[nt], accg[mt][nt]);                    \
          accu[mt][nt] = MFMA_BF16(af[mt], bu[nt], accu[mt][nt]);                    \
        }                                                                            \
    }                                                                                \
  }

  MSTAGE(0, 0);
  MSTAGE(1, 64);
  for (int kt = 0; kt < 16; ++kt) {
    if (kt < 15) {
      asm volatile("s_waitcnt vmcnt(8)" ::: "memory");  // tile kt landed
    } else {
      asm volatile("s_waitcnt vmcnt(0)" ::: "memory");
    }
    SBAR; SCHB;
    MCOMP(kt & 1);
    SCHB; SBAR;                    // all waves done reading buf before overwrite
    if (kt + 2 < 16) MSTAGE(kt & 1, (kt + 2) << 6);
  }
#undef MSTAGE
#undef MCOMP
#pragma unroll
  for (int mt = 0; mt < 8; ++mt)
#pragma unroll
    for (int r = 0; r < 4; ++r) {
      int rl = 128 * wr + 16 * mt + quad * 4 + r;
      int grow = m0 + rl;
      if (grow < cnt) {
        size_t rbase = (size_t)(aoff + grow) * FFI;
#pragma unroll
        for (int nt = 0; nt < 2; ++nt) {
          int col = n0 + 32 * wc + 16 * nt + l16;
          float gv = accg[mt][nt][r];
          float uv = accu[mt][nt][r];
          float a = gv / (1.0f + __expf(-gv)) * uv;
          Abuf[rbase + col] = f2bf(a);
        }
      }
    }
}

// -- MoE down GEMM: 128m x 256n, split-K x2, depth-2 counted pipeline --
__global__ __launch_bounds__(512, 2) void k_moe_y(
    const u16* __restrict__ Abuf, const u16* __restrict__ W2,
    const int* __restrict__ counts, const int* __restrict__ offs,
    float* __restrict__ ybuf) {
  const int e = blockIdx.z >> 1;
  const int sk = blockIdx.z & 1;
  const int cnt = counts[e];
  const int m0 = blockIdx.y * 128;
  if (m0 >= cnt) return;
  const int n0 = blockIdx.x * 256;
  const int kbase = sk * 1408;  // 2816 / 2
  const u16* We = W2 + (size_t)e * HID * FFI;
  const int aoff = offs[e];
  __shared__ u16 As[2][128 * 64], Bs[2][256 * 64];  // 96 KiB
  const int tid = threadIdx.x, wid = tid >> 6, lane = tid & 63;
  const int quad = lane >> 4, l16 = lane & 15;
  const int wr = wid >> 2, wc = wid & 3;  // wave: 64m x 64n
  const int sr = lane >> 3;
  const int scs = (((lane & 7) ^ sr) * 8);
  const int rx = l16 & 7;
  int arow[2];
#pragma unroll
  for (int it = 0; it < 2; ++it) {
    int row = (wid * 2 + it) * 8 + sr;   // seg 0..15 -> rows 0..127
    int ra = m0 + row;
    if (ra > cnt - 1) ra = cnt - 1;
    arow[it] = aoff + ra;
  }
  f32x4 acc[4][4] = {};

  // 6 gload_lds per wave per tile
#define YSTAGE(buf, k0)                                                              \
  {                                                                                  \
    _Pragma("unroll") for (int it = 0; it < 2; ++it) {                               \
      int seg = wid * 2 + it;                                                        \
      gload_lds16(&Abuf[(size_t)arow[it] * FFI + (k0) + scs], &As[buf][seg * 512]);  \
    }                                                                                \
    _Pragma("unroll") for (int it = 0; it < 4; ++it) {                               \
      int seg = wid * 4 + it;                                                        \
      int row = seg * 8 + sr;                                                        \
      gload_lds16(&We[(size_t)(n0 + row) * FFI + (k0) + scs], &Bs[buf][seg * 512]);  \
    }                                                                                \
  }
#define YCOMP(buf)                                                                   \
  {                                                                                  \
    _Pragma("unroll") for (int ks = 0; ks < 2; ++ks) {                               \
      const int cof = ((((ks << 2) | quad) ^ rx) << 3);                              \
      short8 af[4], bf[4];                                                           \
      _Pragma("unroll") for (int t = 0; t < 4; ++t)                                  \
        af[t] = *(const short8*)&As[buf][(64 * wr + 16 * t + l16) * 64 + cof];       \
      _Pragma("unroll") for (int t = 0; t < 4; ++t)                                  \
        bf[t] = *(const short8*)&Bs[buf][(64 * wc + 16 * t + l16) * 64 + cof];       \
      _Pragma("unroll") for (int mt = 0; mt < 4; ++mt)                               \
        _Pragma("unroll") for (int nt = 0; nt < 4; ++nt)                             \
            acc[mt][nt] = MFMA_BF16(af[mt], bf[nt], acc[mt][nt]);                    \
    }                                                                                \
  }

  YSTAGE(0, kbase);
  YSTAGE(1, kbase + 64);
  for (int kt = 0; kt < 22; ++kt) {
    if (kt < 21) {
      asm volatile("s_waitcnt vmcnt(6)" ::: "memory");
    } else {
      asm volatile("s_waitcnt vmcnt(0)" ::: "memory");
    }
    SBAR; SCHB;
    YCOMP(kt & 1);
    SCHB; SBAR;
    if (kt + 2 < 22) YSTAGE(kt & 1, kbase + ((kt + 2) << 6));
  }
#undef YSTAGE
#undef YCOMP
  float* Y = ybuf + (size_t)sk * 2 * SEQ * HID;
#pragma unroll
  for (int mt = 0; mt < 4; ++mt)
#pragma unroll
    for (int r = 0; r < 4; ++r) {
      int rl = 64 * wr + 16 * mt + quad * 4 + r;
      int grow = m0 + rl;
      if (grow < cnt) {
        size_t obase = (size_t)(aoff + grow) * HID;
#pragma unroll
        for (int nt = 0; nt < 4; ++nt) {
          int col = n0 + 64 * wc + 16 * nt + l16;
          Y[obase + col] = acc[mt][nt][r];
        }
      }
    }
}

// ---- final gather: out[t] = w0*(y0[s0]+y1[s0]) + w1*(y0[s1]+y1[s1]) ----
__global__ __launch_bounds__(256) void k_moe_out(
    const float* __restrict__ yb, const int* __restrict__ offs,
    const int* __restrict__ tok_slot, const float* __restrict__ tok_pw,
    float* __restrict__ out0) {
  const int t = blockIdx.x, tid = threadIdx.x;
  const int v0 = tok_slot[2 * t], v1 = tok_slot[2 * t + 1];
  const float w0 = tok_pw[2 * t], w1 = tok_pw[2 * t + 1];
  const size_t g0 = (size_t)(offs[v0 >> 11] + (v0 & (SEQ - 1))) * HID;
  const size_t g1 = (size_t)(offs[v1 >> 11] + (v1 & (SEQ - 1))) * HID;
  const size_t YP = (size_t)2 * SEQ * HID;
  const int c = tid * 4;
  float4 a0 = *(const float4*)&yb[g0 + c];
  float4 b0 = *(const float4*)&yb[YP + g0 + c];
  float4 a1 = *(const float4*)&yb[g1 + c];
  float4 b1 = *(const float4*)&yb[YP + g1 + c];
  float4 r;
  r.x = w0 * (a0.x + b0.x) + w1 * (a1.x + b1.x);
  r.y = w0 * (a0.y + b0.y) + w1 * (a1.y + b1.y);
  r.z = w0 * (a0.z + b0.z) + w1 * (a1.z + b1.z);
  r.w = w0 * (a0.w + b0.w) + w1 * (a1.w + b1.w);
  *(float4*)&out0[(size_t)t * HID + c] = r;
}

extern "C" void kernel_launch(void* const* d_in, const int* in_sizes, int n_in,
                              void* d_out, int out_size, void* d_ws, size_t ws_size,
                              hipStream_t stream) {
  const float* hs   = (const float*)d_in[0];
  const float* wqkv = (const float*)d_in[2];
  const float* wo   = (const float*)d_in[3];
  const float* rwt  = (const float*)d_in[4];
  const float* wsx  = (const float*)d_in[5];
  const float* w2s  = (const float*)d_in[6];
  const float* ln1  = (const float*)d_in[7];
  const float* ln2  = (const float*)d_in[8];
  float* out0 = (float*)d_out;                       // MoE output (f32)
  float* out1 = out0 + (size_t)SEQ * HID;            // residual2 (f32)

  char* p = (char*)d_ws;
  u16* xn       = (u16*)p;   p += (size_t)SEQ * HID * 2;
  u16* qkv      = (u16*)p;   p += (size_t)SEQ * QKVD * 2;
  u16* ob       = (u16*)p;   p += (size_t)SEQ * HID * 2;
  float* of     = (float*)p; p += (size_t)2 * SEQ * HID * 4;  // 2 split planes
  int* counts   = (int*)p;   p += 32;
  int* offs     = (int*)p;   p += 64;
  int* tok_idx  = (int*)p;   p += (size_t)NEXP * SEQ * 4;
  int* tok_slot = (int*)p;   p += (size_t)2 * SEQ * 4;
  float* tok_pw = (float*)p; p += (size_t)2 * SEQ * 4;
  u16* abuf     = (u16*)p;   p += (size_t)2 * SEQ * FFI * 2;
  float* ybuf   = (float*)p; p += (size_t)2 * 2 * SEQ * HID * 4;  // 2 sk planes
  u16* ws_b     = (u16*)p;   p += (size_t)NEXP * 2 * FFI * HID * 2;
  u16* w2s_b    = (u16*)p;   p += (size_t)NEXP * HID * FFI * 2;

  u16* tb = xn;  // alias: xn dead after QKV GEMM

  hipMemsetAsync(counts, 0, 32, stream);

  k_prep<<<SEQ, 256, 0, stream>>>(hs, ln1, xn);
  // QKV: M=2048, N=1536, K=1024, full-K, bf16 epilogue (B = f32 wqkv direct)
  k_gemm_bt<<<dim3(QKVD / 64, SEQ / 128, 1), 256, 0, stream>>>(
      xn, wqkv, qkv, QKVD, HID, 16, 0);
  // attention + fused ws/w2s conversion
  k_attn_conv<<<NATTN_BLK + NCONV_BLK, 256, 0, stream>>>(
      qkv, ob, wsx, w2s, ws_b, w2s_b);
  // O-proj: M=2048, N=1024, K=1024, split-K x2 (B = f32 wo direct)
  k_gemm_bt<<<dim3(HID / 64, SEQ / 128, 2), 256, 0, stream>>>(
      ob, wo, of, HID, HID, 8, 1);
  k_rms2_router<<<SEQ, 256, 0, stream>>>(of, of + (size_t)SEQ * HID, hs, ln2,
                                         rwt, out1, tb, counts, tok_idx,
                                         tok_slot, tok_pw);
  k_offsets<<<1, 64, 0, stream>>>(counts, offs);
  k_moe_gu<<<dim3(FFI / 128, SEQ / 256, NEXP), 512, 0, stream>>>(
      tb, ws_b, counts, offs, tok_idx, abuf);
  k_moe_y<<<dim3(HID / 256, SEQ / 128, NEXP * 2), 512, 0, stream>>>(
      abuf, w2s_b, counts, offs, ybuf);
  k_moe_out<<<SEQ, 256, 0, stream>>>(ybuf, offs, tok_slot, tok_pw, out0);
}